// Round 5
// baseline (2914.975 us; speedup 1.0000x reference)
//
#include <hip/hip_runtime.h>
#include <math.h>

#define B   64
#define T   512
#define I0  256
#define H   512
#define M   (B*T)

#define NGR 4        // batch groups (16 batches each -> MFMA M=16)
#define BGR 16
#define NCH 16       // col chunks
#define CCH 32       // cols per chunk = 2 MFMA tiles
#define HS_STRIDE 520  // staged-h row stride in ushorts

typedef __attribute__((ext_vector_type(8))) short short8;
typedef __attribute__((ext_vector_type(4))) float floatx4;

static __device__ __forceinline__ unsigned short f2bf(float f) {
  unsigned u = __float_as_uint(f);
  u += 0x7fff + ((u >> 16) & 1);          // RNE
  return (unsigned short)(u >> 16);
}

// ---------------------------------------------------------------------------
// fp32 GEMM for layer-1 input projection: xw[M,H] = x[M,I0] * Wih0[H,I0]^T
// ---------------------------------------------------------------------------
template<int K>
__global__ __launch_bounds__(256)
void gemm_awt(const float* __restrict__ A, const float* __restrict__ W,
              float* __restrict__ C) {
  __shared__ float As[16][68];
  __shared__ float Bs[16][68];
  const int tid = threadIdx.x;
  const int tx = tid & 15, ty = tid >> 4;
  const int m0 = blockIdx.x * 64, n0 = blockIdx.y * 64;
  float acc[4][4] = {};
  for (int k0 = 0; k0 < K; k0 += 16) {
    {
      int e = tid * 4;
      int m = e >> 4, k = e & 15;
      float4 v = *(const float4*)&A[(m0 + m) * K + k0 + k];
      As[k][m] = v.x; As[k+1][m] = v.y; As[k+2][m] = v.z; As[k+3][m] = v.w;
      float4 w = *(const float4*)&W[(n0 + m) * K + k0 + k];
      Bs[k][m] = w.x; Bs[k+1][m] = w.y; Bs[k+2][m] = w.z; Bs[k+3][m] = w.w;
    }
    __syncthreads();
    #pragma unroll
    for (int k = 0; k < 16; ++k) {
      float a[4], w[4];
      *(float4*)a = *(const float4*)&As[k][ty*4];
      *(float4*)w = *(const float4*)&Bs[k][tx*4];
      #pragma unroll
      for (int i = 0; i < 4; ++i)
        #pragma unroll
        for (int j = 0; j < 4; ++j)
          acc[i][j] += a[i] * w[j];
    }
    __syncthreads();
  }
  #pragma unroll
  for (int i = 0; i < 4; ++i) {
    float4 r;
    r.x = acc[i][0]; r.y = acc[i][1]; r.z = acc[i][2]; r.w = acc[i][3];
    *(float4*)&C[(m0 + ty*4 + i) * H + n0 + tx*4] = r;
  }
}

// ---------------------------------------------------------------------------
// Pack [H,H] fp32 weight into bf16 B-fragment lane order.
// ---------------------------------------------------------------------------
__global__ __launch_bounds__(256)
void pack_w(const float* __restrict__ W, unsigned short* __restrict__ dst) {
  int idx = blockIdx.x * 256 + threadIdx.x;   // over 16*2*16*64 = 32768
  int l = idx & 63, i = (idx >> 6) & 15, tau = (idx >> 10) & 1, c = idx >> 11;
  int col = c * CCH + tau * 16 + (l & 15);
  int k0  = i * 32 + (l >> 4) * 8;
  const float* src = &W[col * H + k0];
  unsigned v[4];
  #pragma unroll
  for (int j = 0; j < 4; ++j) {
    unsigned lo = f2bf(src[2*j]);
    unsigned hi = f2bf(src[2*j + 1]);
    v[j] = lo | (hi << 16);
  }
  *(uint4*)&dst[(size_t)idx * 8] = make_uint4(v[0], v[1], v[2], v[3]);
}

// ---------------------------------------------------------------------------
// Fused 2-layer pipelined persistent recurrence, SELF-VALIDATING exchange:
// ring words are (bf16(h)<<16)|(t+1). Consumers poll the data itself until
// the embedded seq matches — detect and load are the same IC round trip.
// No flags, no store-ack barrier; rings double-buffered by timestep parity
// (block barrier between validate and store makes overwrite provably safe).
// Poison 0xAAAAAAAA and zero both have seq!=any expected (expected >= 1).
// ---------------------------------------------------------------------------
__global__ __launch_bounds__(256)
void rnn_fused(const float* __restrict__ xw,
               const unsigned short* __restrict__ wp0,  // Whh0 packed
               const unsigned short* __restrict__ wp1,  // Wih1 packed
               const unsigned short* __restrict__ wp2,  // Whh1 packed
               unsigned* __restrict__ ring0,            // [2][B][H] u32
               unsigned* __restrict__ ring1,            // [2][B][H] u32
               float* __restrict__ dout)                // [B][T][H]
{
  extern __shared__ unsigned short smem[];
  unsigned short* Ws0 = smem;             // [2][16][64][8] = 16384 us
  unsigned short* Wi1 = Ws0 + 16384;
  unsigned short* Ws1 = Wi1 + 16384;
  unsigned short* hs0 = Ws1 + 16384;      // [16][HS_STRIDE]
  unsigned short* hs1 = hs0 + 8320;

  const int tid   = threadIdx.x;
  const int g     = blockIdx.x & 3;
  const int chunk = blockIdx.x >> 2;
  const int c0    = chunk * CCH;
  const int b0    = g * BGR;
  const int wv    = tid >> 6;
  const int lane  = tid & 63;
  const int mrow  = lane & 15;
  const int quad  = lane >> 4;

  // stage packed weight slices
  {
    const uint4* s0 = (const uint4*)(wp0 + (size_t)chunk * 16384);
    const uint4* s1 = (const uint4*)(wp1 + (size_t)chunk * 16384);
    const uint4* s2 = (const uint4*)(wp2 + (size_t)chunk * 16384);
    uint4* d0 = (uint4*)Ws0; uint4* d1 = (uint4*)Wi1; uint4* d2 = (uint4*)Ws1;
    for (int i = tid; i < 2048; i += 256) { d0[i] = s0[i]; d1[i] = s1[i]; d2[i] = s2[i]; }
  }
  // zero hs1 (read by layer-2 MFMA at r==1 before first staging)
  for (int i = tid; i < 2080; i += 256) ((unsigned long long*)hs1)[i] = 0ULL;
  __syncthreads();

  for (int r = 0; r <= T; ++r) {
    // ---- xw prefetch (independent; latency overlaps the poll) ----
    float xv[4];
    if (wv < 2 && r < T) {
      const int ccol = c0 + wv * 16 + mrow;
      #pragma unroll
      for (int i = 0; i < 4; ++i)
        xv[i] = xw[((size_t)(b0 + quad * 4 + i) * T + r) * H + ccol];
    }

    // ---- fused poll+load: validate embedded seqs, retry only pending ----
    unsigned long long v0[16], v1[16];
    unsigned pend0 = (r >= 1) ? 0xffffu : 0u;
    unsigned pend1 = (r >= 2) ? 0xffffu : 0u;
    const unsigned s0q = (unsigned)r;        // ring0: h0_{r-1} has seq r
    const unsigned s1q = (unsigned)(r - 1);  // ring1: h1_{r-2} has seq r-1
    const unsigned long long* r0p =
        (const unsigned long long*)(ring0 + (size_t)((r - 1) & 1) * B * H + b0 * H);
    const unsigned long long* r1p =
        (const unsigned long long*)(ring1 + (size_t)((r - 2) & 1) * B * H + b0 * H);
    long guard = 0;
    while (pend0 | pend1) {
      #pragma unroll
      for (int j = 0; j < 16; ++j)
        if (pend0 & (1u << j))
          v0[j] = __hip_atomic_load(r0p + j * 256 + tid,
                                    __ATOMIC_RELAXED, __HIP_MEMORY_SCOPE_AGENT);
      #pragma unroll
      for (int j = 0; j < 16; ++j)
        if (pend1 & (1u << j))
          v1[j] = __hip_atomic_load(r1p + j * 256 + tid,
                                    __ATOMIC_RELAXED, __HIP_MEMORY_SCOPE_AGENT);
      #pragma unroll
      for (int j = 0; j < 16; ++j)
        if (pend0 & (1u << j)) {
          unsigned lo = (unsigned)v0[j], hi = (unsigned)(v0[j] >> 32);
          if ((((lo ^ s0q) | (hi ^ s0q)) & 0xffffu) == 0) pend0 &= ~(1u << j);
        }
      #pragma unroll
      for (int j = 0; j < 16; ++j)
        if (pend1 & (1u << j)) {
          unsigned lo = (unsigned)v1[j], hi = (unsigned)(v1[j] >> 32);
          if ((((lo ^ s1q) | (hi ^ s1q)) & 0xffffu) == 0) pend1 &= ~(1u << j);
        }
      if (!(pend0 | pend1)) break;
      __builtin_amdgcn_s_sleep(1);
      if (++guard > 300000L) break;   // safety valve: terminate, fail loudly
    }

    __syncthreads();   // prev round's LDS reads complete before overwrite

    // ---- extract bf16 (high halves) into LDS: row j, cols 2*tid..2*tid+1
    if (r >= 1) {
      #pragma unroll
      for (int j = 0; j < 16; ++j) {
        unsigned d = ((unsigned)v0[j] >> 16) |
                     ((unsigned)(v0[j] >> 32) & 0xffff0000u);
        *(unsigned*)&hs0[j * HS_STRIDE + 2 * tid] = d;
      }
    }
    if (r >= 2) {
      #pragma unroll
      for (int j = 0; j < 16; ++j) {
        unsigned d = ((unsigned)v1[j] >> 16) |
                     ((unsigned)(v1[j] >> 32) & 0xffff0000u);
        *(unsigned*)&hs1[j * HS_STRIDE + 2 * tid] = d;
      }
    }
    __syncthreads();

    // ---- compute ----
    if (wv < 2) {                       // layer 1, tile wv, step r
      if (r < T) {
        floatx4 acc = {0.f, 0.f, 0.f, 0.f};
        if (r >= 1) {
          const unsigned short* wb = Ws0 + wv * 8192;
          const unsigned short* ha = hs0 + mrow * HS_STRIDE + quad * 8;
          #pragma unroll
          for (int i = 0; i < 16; ++i) {
            short8 a = *(const short8*)(ha + i * 32);
            short8 b = *(const short8*)(wb + (i * 64 + lane) * 8);
            acc = __builtin_amdgcn_mfma_f32_16x16x32_bf16(a, b, acc, 0, 0, 0);
          }
        }
        const int ccol = c0 + wv * 16 + mrow;
        unsigned* rdst = ring0 + (size_t)(r & 1) * B * H;
        const unsigned seq = (unsigned)(r + 1);
        #pragma unroll
        for (int i = 0; i < 4; ++i) {
          int b = b0 + quad * 4 + i;
          float h = tanhf(acc[i] + xv[i]);
          unsigned w = ((unsigned)f2bf(h) << 16) | seq;
          __hip_atomic_store(rdst + (size_t)b * H + ccol, w,
                             __ATOMIC_RELAXED, __HIP_MEMORY_SCOPE_AGENT);
        }
      }
    } else {                            // layer 2, tile wv-2, step t2 = r-1
      if (r >= 1) {
        floatx4 acc = {0.f, 0.f, 0.f, 0.f};
        const int tt = wv - 2;
        const unsigned short* wi  = Wi1 + tt * 8192;
        const unsigned short* wh  = Ws1 + tt * 8192;
        const unsigned short* ha0 = hs0 + mrow * HS_STRIDE + quad * 8;
        const unsigned short* ha1 = hs1 + mrow * HS_STRIDE + quad * 8;
        #pragma unroll
        for (int i = 0; i < 16; ++i) {
          short8 a = *(const short8*)(ha0 + i * 32);
          short8 b = *(const short8*)(wi + (i * 64 + lane) * 8);
          acc = __builtin_amdgcn_mfma_f32_16x16x32_bf16(a, b, acc, 0, 0, 0);
        }
        #pragma unroll
        for (int i = 0; i < 16; ++i) {
          short8 a = *(const short8*)(ha1 + i * 32);
          short8 b = *(const short8*)(wh + (i * 64 + lane) * 8);
          acc = __builtin_amdgcn_mfma_f32_16x16x32_bf16(a, b, acc, 0, 0, 0);
        }
        const int ccol = c0 + tt * 16 + mrow;
        const int t2 = r - 1;
        unsigned* rdst = ring1 + (size_t)(t2 & 1) * B * H;
        const unsigned seq = (unsigned)(t2 + 1);
        #pragma unroll
        for (int i = 0; i < 4; ++i) {
          int b = b0 + quad * 4 + i;
          float h = tanhf(acc[i]);
          dout[((size_t)b * T + t2) * H + ccol] = h;   // plain cached store
          unsigned w = ((unsigned)f2bf(h) << 16) | seq;
          __hip_atomic_store(rdst + (size_t)b * H + ccol, w,
                             __ATOMIC_RELAXED, __HIP_MEMORY_SCOPE_AGENT);
        }
      }
    }
    // no end-of-round barrier: stores are fire-and-forget; consumers gate
    // on the embedded seq, and the poll->barrier->store order above makes
    // parity-buffer overwrite impossible before group-wide validation.
  }
}

#define SMEM_BYTES ((3 * 16384 + 2 * 8320) * 2)   // 131584

// ws: [0,64MB) xw | +0/512K/1M packed W x3 | +1.5M ring0 (256K) | +2M ring1
extern "C" void kernel_launch(void* const* d_in, const int* in_sizes, int n_in,
                              void* d_out, int out_size, void* d_ws, size_t ws_size,
                              hipStream_t stream) {
  const float* x    = (const float*)d_in[0];
  const float* Wih0 = (const float*)d_in[1];
  const float* Whh0 = (const float*)d_in[2];
  const float* Wih1 = (const float*)d_in[3];
  const float* Whh1 = (const float*)d_in[4];
  float* out = (float*)d_out;

  char* ws = (char*)d_ws;
  float* xw = (float*)ws;
  unsigned short* wp0 = (unsigned short*)(ws + (size_t)64*1024*1024);
  unsigned short* wp1 = (unsigned short*)(ws + (size_t)64*1024*1024 + 512*1024);
  unsigned short* wp2 = (unsigned short*)(ws + (size_t)64*1024*1024 + 1024*1024);
  unsigned* ring0 = (unsigned*)(ws + (size_t)64*1024*1024 + 1536*1024);
  unsigned* ring1 = (unsigned*)(ws + (size_t)64*1024*1024 + 2048*1024);

  hipFuncSetAttribute((const void*)rnn_fused,
                      hipFuncAttributeMaxDynamicSharedMemorySize, SMEM_BYTES);

  pack_w<<<128, 256, 0, stream>>>(Whh0, wp0);
  pack_w<<<128, 256, 0, stream>>>(Wih1, wp1);
  pack_w<<<128, 256, 0, stream>>>(Whh1, wp2);

  dim3 gg(M/64, H/64);
  gemm_awt<I0><<<gg, 256, 0, stream>>>(x, Wih0, xw);

  rnn_fused<<<NGR * NCH, 256, SMEM_BYTES, stream>>>(
      xw, wp0, wp1, wp2, ring0, ring1, out);
}